// Round 8
// baseline (478.962 us; speedup 1.0000x reference)
//
#include <hip/hip_runtime.h>
#include <hip/hip_fp16.h>

#define B_ 4
#define S_ 2048
#define H_ 1024
#define M_ (B_ * S_)   // 8192 flattened rows of x / q / k / v
#define NBLK 512       // all co-resident: launch_bounds(256,2) => >=2 blocks/CU

typedef _Float16 f16;
typedef _Float16 f16x8 __attribute__((ext_vector_type(8)));
typedef _Float16 f16x4 __attribute__((ext_vector_type(4)));
typedef float f32x4 __attribute__((ext_vector_type(4)));

typedef __attribute__((address_space(3))) unsigned int* lds_u32p;
typedef const __attribute__((address_space(1))) unsigned int* gbl_u32p;

// async global->LDS, 16B per lane; LDS dest is wave-uniform base + lane*16
__device__ __forceinline__ void stage16(const f16* g, f16* l) {
  __builtin_amdgcn_global_load_lds((gbl_u32p)g, (lds_u32p)l, 16, 0, 0);
}

// ---------------------------------------------------------------------------
// Device-scope phase barrier. Monotonic counter (no reset -> no wrap races).
// AGENT-scope acq_rel RMW / acquire load emit the per-XCD L2 writeback /
// invalidate needed for cross-XCD visibility on gfx950 (G16).
__device__ __forceinline__ void gsync(unsigned* bar, unsigned target) {
  __syncthreads();  // all block's stores drained (vmcnt0) before arrive
  if (threadIdx.x == 0) {
    __hip_atomic_fetch_add(bar, 1u, __ATOMIC_ACQ_REL, __HIP_MEMORY_SCOPE_AGENT);
    while (__hip_atomic_load(bar, __ATOMIC_ACQUIRE, __HIP_MEMORY_SCOPE_AGENT) < target)
      __builtin_amdgcn_s_sleep(8);
  }
  __syncthreads();
}

// ---------------------------------------------------------------------------
// r4-proven GEMM tile body: NT fp16, 128x128 tile, BK=64 (two BK=32 sub-chunks
// per barrier), 16x16x32 MFMA, 4x4 acc per wave.
template <int OUT_F16>
__device__ __forceinline__ void gemm_tile(
    const f16* __restrict__ A, const f16* __restrict__ Bm, void* __restrict__ C,
    int lda, int ldb, int ldc, int K, long sA, long sB, long sC, float alpha,
    int bx, int by, int bz, int t, f16* As, f16* Bs) {
  const int wave = t >> 6, lane = t & 63;
  const int quad = lane >> 4, l16 = lane & 15;
  const int wm = (wave & 1) * 64, wn = (wave >> 1) * 64;
  const f16* Ab = A + bz * sA + (long)bx * 128 * lda;
  const f16* Bb = Bm + bz * sB + (long)by * 128 * ldb;
  const int r0 = t >> 2, c8 = (t & 3) * 8;
  f32x4 acc[4][4] = {};
  for (int k0 = 0; k0 < K; k0 += 64) {
    __syncthreads();
    stage16(Ab + (long)r0 * lda + k0 + c8,             As + t * 8);
    stage16(Ab + (long)(r0 + 64) * lda + k0 + c8,      As + 2048 + t * 8);
    stage16(Ab + (long)r0 * lda + k0 + 32 + c8,        As + 4096 + t * 8);
    stage16(Ab + (long)(r0 + 64) * lda + k0 + 32 + c8, As + 6144 + t * 8);
    stage16(Bb + (long)r0 * ldb + k0 + c8,             Bs + t * 8);
    stage16(Bb + (long)(r0 + 64) * ldb + k0 + c8,      Bs + 2048 + t * 8);
    stage16(Bb + (long)r0 * ldb + k0 + 32 + c8,        Bs + 4096 + t * 8);
    stage16(Bb + (long)(r0 + 64) * ldb + k0 + 32 + c8, Bs + 6144 + t * 8);
    __syncthreads();
#pragma unroll
    for (int kk = 0; kk < 2; kk++) {
      f16x8 af[4], bf[4];
#pragma unroll
      for (int i = 0; i < 4; i++) {
        af[i] = *(const f16x8*)&As[kk * 4096 + (wm + i * 16 + l16) * 32 + quad * 8];
        bf[i] = *(const f16x8*)&Bs[kk * 4096 + (wn + i * 16 + l16) * 32 + quad * 8];
      }
#pragma unroll
      for (int i = 0; i < 4; i++)
#pragma unroll
        for (int j = 0; j < 4; j++)
          acc[i][j] = __builtin_amdgcn_mfma_f32_16x16x32_f16(af[i], bf[j], acc[i][j], 0, 0, 0);
    }
  }
  const long mb = (long)bx * 128 + wm;
  const long nb = (long)by * 128 + wn;
#pragma unroll
  for (int i = 0; i < 4; i++)
#pragma unroll
    for (int j = 0; j < 4; j++) {
      long m = mb + i * 16 + quad * 4;
      long n = nb + j * 16 + l16;
#pragma unroll
      for (int r = 0; r < 4; r++) {
        float v = acc[i][j][r] * alpha;
        if (OUT_F16)
          ((f16*)C)[bz * sC + (m + r) * ldc + n] = (f16)v;
        else
          ((float*)C)[bz * sC + (m + r) * ldc + n] = v;
      }
    }
}

// ---------------------------------------------------------------------------
// One persistent kernel, 5 phases separated by device-scope barriers.
// Phase work divides exactly across NBLK=512 blocks (no imbalance):
//   downconvert 22 f32x4/thread | qkv 3 tiles | scores 2 | softmax 16 rows | av 1
__global__ __launch_bounds__(256, 2)
void fused_all(const float* __restrict__ x, const float* __restrict__ Wq,
               const float* __restrict__ bq, const float* __restrict__ Wk,
               const float* __restrict__ bk, const float* __restrict__ Wv,
               const float* __restrict__ bv, f16* __restrict__ xh,
               f16* __restrict__ Wh, f16* __restrict__ qkv,
               f16* __restrict__ vT, f16* __restrict__ sc,
               float* __restrict__ out, unsigned* __restrict__ bar) {
  __shared__ __align__(16) f16 As[2 * 128 * 32];
  __shared__ __align__(16) f16 Bs[2 * 128 * 32];
  __shared__ float redm[4], reds[4];
  const int t = threadIdx.x;
  const int blk = blockIdx.x;
  const int wave = t >> 6, lane = t & 63;

  // ---- Phase 1: downconvert x (2097152 f32x4) + Wq|Wk|Wv (786432) ----
  {
    const int NX = M_ * H_ / 4;  // 2097152
    for (int i = blk * 256 + t; i < NX + 3 * H_ * H_ / 4; i += NBLK * 256) {
      const float* src;
      f16* dst;
      int idx;
      if (i < NX) { src = (const float*)0; dst = xh; idx = i;
        f32x4 v = ((const f32x4*)x)[idx];
        f16x4 h;
#pragma unroll
        for (int c = 0; c < 4; c++) h[c] = (f16)v[c];
        ((f16x4*)xh)[idx] = h;
      } else {
        int j = i - NX;                       // 0..786431
        int sel = j >> 18;                    // 262144 f32x4 per W
        src = sel == 0 ? Wq : (sel == 1 ? Wk : Wv);
        f32x4 v = ((const f32x4*)src)[j & 262143];
        f16x4 h;
#pragma unroll
        for (int c = 0; c < 4; c++) h[c] = (f16)v[c];
        ((f16x4*)Wh)[j] = h;
      }
    }
  }
  gsync(bar, NBLK);

  // ---- Phase 2: fused QKV projection (1536 tiles, 3 per block) ----
  for (int it = 0; it < 3; it++) {
    const int T = it * NBLK + blk;
    const int bx = T & 63, by = T >> 6;
    const int sel = by >> 3;                 // 0=q 1=k 2=v
    const int ntile = (by & 7) * 128, mtile = bx * 128;
    const f16* Ab = xh + (long)mtile * H_;
    const f16* Bb = Wh + (long)sel * H_ * H_ + (long)ntile * H_;
    const int quad = lane >> 4, l16 = lane & 15;
    const int wm = (wave & 1) * 64, wn = (wave >> 1) * 64;
    const int r0 = t >> 2, c8 = (t & 3) * 8;
    f32x4 acc[4][4] = {};
    for (int k0 = 0; k0 < H_; k0 += 64) {
      __syncthreads();
      stage16(Ab + (long)r0 * H_ + k0 + c8,             As + t * 8);
      stage16(Ab + (long)(r0 + 64) * H_ + k0 + c8,      As + 2048 + t * 8);
      stage16(Ab + (long)r0 * H_ + k0 + 32 + c8,        As + 4096 + t * 8);
      stage16(Ab + (long)(r0 + 64) * H_ + k0 + 32 + c8, As + 6144 + t * 8);
      stage16(Bb + (long)r0 * H_ + k0 + c8,             Bs + t * 8);
      stage16(Bb + (long)(r0 + 64) * H_ + k0 + c8,      Bs + 2048 + t * 8);
      stage16(Bb + (long)r0 * H_ + k0 + 32 + c8,        Bs + 4096 + t * 8);
      stage16(Bb + (long)(r0 + 64) * H_ + k0 + 32 + c8, Bs + 6144 + t * 8);
      __syncthreads();
#pragma unroll
      for (int kk = 0; kk < 2; kk++) {
        f16x8 ah[4], bh[4];
#pragma unroll
        for (int i = 0; i < 4; i++) {
          ah[i] = *(const f16x8*)&As[kk * 4096 + (wm + i * 16 + l16) * 32 + quad * 8];
          bh[i] = *(const f16x8*)&Bs[kk * 4096 + (wn + i * 16 + l16) * 32 + quad * 8];
        }
#pragma unroll
        for (int i = 0; i < 4; i++)
#pragma unroll
          for (int j = 0; j < 4; j++)
            acc[i][j] = __builtin_amdgcn_mfma_f32_16x16x32_f16(ah[i], bh[j], acc[i][j], 0, 0, 0);
      }
    }
    const float* bias = sel == 0 ? bq : (sel == 1 ? bk : bv);
    if (sel == 2) {
      // V transposed: vT[(b*H + n)*S + t_pos], b = m>>11, t_pos = m&2047.
#pragma unroll
      for (int j = 0; j < 4; j++) {
        int n = ntile + wn + j * 16 + l16;
        float bb = bias[n];
#pragma unroll
        for (int i = 0; i < 4; i++) {
          int m = mtile + wm + i * 16 + quad * 4;
          f16x4 pack;
#pragma unroll
          for (int r = 0; r < 4; r++) pack[r] = (f16)(acc[i][j][r] + bb);
          *(f16x4*)&vT[((long)(m >> 11) * H_ + n) * S_ + (m & 2047)] = pack;
        }
      }
    } else {
      f16* o = qkv + (long)sel * M_ * H_;
#pragma unroll
      for (int j = 0; j < 4; j++) {
        int n = ntile + wn + j * 16 + l16;
        float bb = bias[n];
#pragma unroll
        for (int i = 0; i < 4; i++) {
          int m = mtile + wm + i * 16 + quad * 4;
#pragma unroll
          for (int r = 0; r < 4; r++)
            o[(long)(m + r) * H_ + n] = (f16)(acc[i][j][r] + bb);
        }
      }
    }
  }
  gsync(bar, 2 * NBLK);

  // ---- Phase 3: scores = quantize(q @ k^T / 32)  (1024 tiles, 2/block) ----
  for (int it = 0; it < 2; it++) {
    const int T = it * NBLK + blk;
    gemm_tile<1>(qkv, qkv + (size_t)M_ * H_, sc, H_, H_, S_, H_,
                 (long)S_ * H_, (long)S_ * H_, (long)S_ * S_, 0.03125f,
                 T & 15, (T >> 4) & 15, T >> 8, t, As, Bs);
  }
  gsync(bar, 3 * NBLK);

  // ---- Phase 4: attn = quantize(softmax(sc)) in-place (16 rows/block) ----
  for (int r = 0; r < 16; r++) {
    f16* p = sc + ((long)blk * 16 + r) * S_;
    f16x8 v = ((const f16x8*)p)[t];
    float f[8];
    float m = -3.0e38f;
#pragma unroll
    for (int c = 0; c < 8; c++) { f[c] = (float)v[c]; m = fmaxf(m, f[c]); }
#pragma unroll
    for (int o = 32; o > 0; o >>= 1) m = fmaxf(m, __shfl_xor(m, o));
    if (lane == 0) redm[wave] = m;
    __syncthreads();
    m = fmaxf(fmaxf(redm[0], redm[1]), fmaxf(redm[2], redm[3]));
    float s = 0.f, e[8];
#pragma unroll
    for (int c = 0; c < 8; c++) { e[c] = __expf(f[c] - m); s += e[c]; }
#pragma unroll
    for (int o = 32; o > 0; o >>= 1) s += __shfl_xor(s, o);
    if (lane == 0) reds[wave] = s;
    __syncthreads();
    s = reds[0] + reds[1] + reds[2] + reds[3];
    float inv = 1.0f / s;
    f16x8 ov;
#pragma unroll
    for (int c = 0; c < 8; c++) ov[c] = (f16)(e[c] * inv);
    ((f16x8*)p)[t] = ov;
    __syncthreads();  // redm/reds reuse across rows
  }
  gsync(bar, 4 * NBLK);

  // ---- Phase 5: out = attn @ vT^T (512 tiles, 1/block, fp32 epilogue) ----
  gemm_tile<0>(sc, vT, out, S_, S_, H_, S_,
               (long)S_ * S_, (long)H_ * S_, (long)S_ * H_, 1.0f,
               blk & 15, (blk >> 4) & 7, blk >> 7, t, As, Bs);
}

// ---------------------------------------------------------------------------
extern "C" void kernel_launch(void* const* d_in, const int* in_sizes, int n_in,
                              void* d_out, int out_size, void* d_ws, size_t ws_size,
                              hipStream_t stream) {
  (void)in_sizes; (void)n_in; (void)out_size; (void)ws_size;
  const float* x  = (const float*)d_in[0];
  const float* Wq = (const float*)d_in[1];
  const float* bq = (const float*)d_in[2];
  const float* Wk = (const float*)d_in[3];
  const float* bk = (const float*)d_in[4];
  const float* Wv = (const float*)d_in[5];
  const float* bv = (const float*)d_in[6];

  unsigned* bar = (unsigned*)d_ws;                         // 256 B barrier area
  char* ws = (char*)d_ws + 256;
  f16* xh  = (f16*)ws; ws += (size_t)M_ * H_ * 2;          // 16 MiB
  f16* Wh  = (f16*)ws; ws += (size_t)3 * H_ * H_ * 2;      // 6 MiB
  f16* qkv = (f16*)ws; ws += (size_t)2 * M_ * H_ * 2;      // 32 MiB (q, k)
  f16* vT  = (f16*)ws; ws += (size_t)B_ * H_ * S_ * 2;     // 16 MiB
  f16* sc  = (f16*)ws; ws += (size_t)B_ * S_ * S_ * 2;     // 32 MiB

  hipMemsetAsync(bar, 0, 256, stream);  // barrier counter = 0 (ws is poisoned)
  fused_all<<<NBLK, 256, 0, stream>>>(x, Wq, bq, Wk, bk, Wv, bv,
                                      xh, Wh, qkv, vT, sc, (float*)d_out, bar);
}

// Round 9
// 338.501 us; speedup vs baseline: 1.4149x; 1.4149x over previous
//
#include <hip/hip_runtime.h>
#include <hip/hip_fp16.h>

#define B_ 4
#define S_ 2048
#define H_ 1024
#define M_ (B_ * S_)  // 8192 flattened rows of x / q / k / v

typedef _Float16 f16;
typedef _Float16 f16x8 __attribute__((ext_vector_type(8)));
typedef _Float16 f16x4 __attribute__((ext_vector_type(4)));
typedef float f32x4 __attribute__((ext_vector_type(4)));

typedef __attribute__((address_space(3))) unsigned int* lds_u32p;
typedef const __attribute__((address_space(1))) unsigned int* gbl_u32p;

// async global->LDS, 16B per lane; LDS dest is wave-uniform base + lane*16
__device__ __forceinline__ void stage16(const f16* g, f16* l) {
  __builtin_amdgcn_global_load_lds((gbl_u32p)g, (lds_u32p)l, 16, 0, 0);
}

// ---------------------------------------------------------------------------
// One launch: x (8192 blocks) then Wq/Wk/Wv (1024 blocks each) -> fp16 RNE.
__global__ __launch_bounds__(256) void downconvert_all(
    const float* __restrict__ x, const float* __restrict__ W0,
    const float* __restrict__ W1, const float* __restrict__ W2,
    f16* __restrict__ xh, f16* __restrict__ Wh) {
  const int b = blockIdx.x;
  const float* src;
  f16* dst;
  long i;
  if (b < M_ * H_ / 1024) {  // 8192 x-blocks
    src = x; dst = xh;
    i = (long)b * 256 + threadIdx.x;
  } else {
    const int wb = b - M_ * H_ / 1024;
    const int sel = wb >> 10;               // 1024 blocks per W
    src = sel == 0 ? W0 : (sel == 1 ? W1 : W2);
    dst = Wh + (long)sel * H_ * H_;
    i = (long)(wb & 1023) * 256 + threadIdx.x;
  }
  f32x4 v = ((const f32x4*)src)[i];
  f16x4 h;
#pragma unroll
  for (int c = 0; c < 4; c++) h[c] = (f16)v[c];
  ((f16x4*)dst)[i] = h;
}

// ---------------------------------------------------------------------------
// Fused QKV projection (round-4 proven): qkv[sel][m][n] = fp16round(x.W + b).
// NT GEMM, 128x128 tile, BK=64 as two BK=32 sub-chunks per barrier, 16x16x32
// MFMA, 4x4 acc/wave. sel==2 (V) written TRANSPOSED to vT[b][h][t].
__global__ __launch_bounds__(256, 2)
void qkv_gemm(const f16* __restrict__ xh, const f16* __restrict__ Wh,
              const float* __restrict__ bq, const float* __restrict__ bk,
              const float* __restrict__ bv, f16* __restrict__ qkv,
              f16* __restrict__ vT) {
  __shared__ __align__(16) f16 As[2 * 128 * 32];  // [chunk0 | chunk1]
  __shared__ __align__(16) f16 Bs[2 * 128 * 32];
  const int t = threadIdx.x;
  const int wave = t >> 6, lane = t & 63;
  const int quad = lane >> 4, l16 = lane & 15;
  const int wm = (wave & 1) * 64, wn = (wave >> 1) * 64;
  const int sel = blockIdx.y >> 3;             // 0=q 1=k 2=v
  const int ntile = (blockIdx.y & 7) * 128;
  const int mtile = blockIdx.x * 128;

  const f16* Ab = xh + (long)mtile * H_;
  const f16* Bb = Wh + (long)sel * H_ * H_ + (long)ntile * H_;

  const int r0 = t >> 2;        // staging row 0..63
  const int c8 = (t & 3) * 8;   // staging col (halfs)

  f32x4 acc[4][4] = {};

  for (int k0 = 0; k0 < H_; k0 += 64) {
    __syncthreads();
    stage16(Ab + (long)r0 * H_ + k0 + c8,             As + t * 8);
    stage16(Ab + (long)(r0 + 64) * H_ + k0 + c8,      As + 2048 + t * 8);
    stage16(Ab + (long)r0 * H_ + k0 + 32 + c8,        As + 4096 + t * 8);
    stage16(Ab + (long)(r0 + 64) * H_ + k0 + 32 + c8, As + 6144 + t * 8);
    stage16(Bb + (long)r0 * H_ + k0 + c8,             Bs + t * 8);
    stage16(Bb + (long)(r0 + 64) * H_ + k0 + c8,      Bs + 2048 + t * 8);
    stage16(Bb + (long)r0 * H_ + k0 + 32 + c8,        Bs + 4096 + t * 8);
    stage16(Bb + (long)(r0 + 64) * H_ + k0 + 32 + c8, Bs + 6144 + t * 8);
    __syncthreads();
#pragma unroll
    for (int kk = 0; kk < 2; kk++) {
      f16x8 ah[4], bh[4];
#pragma unroll
      for (int i = 0; i < 4; i++) {
        ah[i] = *(const f16x8*)&As[kk * 4096 + (wm + i * 16 + l16) * 32 + quad * 8];
        bh[i] = *(const f16x8*)&Bs[kk * 4096 + (wn + i * 16 + l16) * 32 + quad * 8];
      }
#pragma unroll
      for (int i = 0; i < 4; i++)
#pragma unroll
        for (int j = 0; j < 4; j++)
          acc[i][j] = __builtin_amdgcn_mfma_f32_16x16x32_f16(ah[i], bh[j], acc[i][j], 0, 0, 0);
    }
  }

  const float* bias = sel == 0 ? bq : (sel == 1 ? bk : bv);
  if (sel == 2) {
    // V transposed: vT[(b*H + n)*S + t_pos], b = m>>11, t_pos = m&2047.
#pragma unroll
    for (int j = 0; j < 4; j++) {
      int n = ntile + wn + j * 16 + l16;
      float bb = bias[n];
#pragma unroll
      for (int i = 0; i < 4; i++) {
        int m = mtile + wm + i * 16 + quad * 4;
        f16x4 pack;
#pragma unroll
        for (int r = 0; r < 4; r++) pack[r] = (f16)(acc[i][j][r] + bb);
        *(f16x4*)&vT[((long)(m >> 11) * H_ + n) * S_ + (m & 2047)] = pack;
      }
    }
  } else {
    f16* out = qkv + (long)sel * M_ * H_;
#pragma unroll
    for (int j = 0; j < 4; j++) {
      int n = ntile + wn + j * 16 + l16;
      float bb = bias[n];
#pragma unroll
      for (int i = 0; i < 4; i++) {
        int m = mtile + wm + i * 16 + quad * 4;
#pragma unroll
        for (int r = 0; r < 4; r++)
          out[(long)(m + r) * H_ + n] = (f16)(acc[i][j][r] + bb);
      }
    }
  }
}

// ---------------------------------------------------------------------------
// Scores GEMM (round-4 proven): sc[z][m][n] = fp16(q[m].k[n] / 32).
__global__ __launch_bounds__(256, 2)
void gemm_qk(const f16* __restrict__ A, const f16* __restrict__ Bm,
             f16* __restrict__ C) {
  __shared__ __align__(16) f16 As[2 * 128 * 32];
  __shared__ __align__(16) f16 Bs[2 * 128 * 32];
  const int t = threadIdx.x;
  const int wave = t >> 6, lane = t & 63;
  const int quad = lane >> 4, l16 = lane & 15;
  const int wm = (wave & 1) * 64, wn = (wave >> 1) * 64;
  const f16* Ab = A + (long)blockIdx.z * S_ * H_ + (long)blockIdx.x * 128 * H_;
  const f16* Bb = Bm + (long)blockIdx.z * S_ * H_ + (long)blockIdx.y * 128 * H_;
  const int r0 = t >> 2, c8 = (t & 3) * 8;
  f32x4 acc[4][4] = {};
  for (int k0 = 0; k0 < H_; k0 += 64) {
    __syncthreads();
    stage16(Ab + (long)r0 * H_ + k0 + c8,             As + t * 8);
    stage16(Ab + (long)(r0 + 64) * H_ + k0 + c8,      As + 2048 + t * 8);
    stage16(Ab + (long)r0 * H_ + k0 + 32 + c8,        As + 4096 + t * 8);
    stage16(Ab + (long)(r0 + 64) * H_ + k0 + 32 + c8, As + 6144 + t * 8);
    stage16(Bb + (long)r0 * H_ + k0 + c8,             Bs + t * 8);
    stage16(Bb + (long)(r0 + 64) * H_ + k0 + c8,      Bs + 2048 + t * 8);
    stage16(Bb + (long)r0 * H_ + k0 + 32 + c8,        Bs + 4096 + t * 8);
    stage16(Bb + (long)(r0 + 64) * H_ + k0 + 32 + c8, Bs + 6144 + t * 8);
    __syncthreads();
#pragma unroll
    for (int kk = 0; kk < 2; kk++) {
      f16x8 af[4], bf[4];
#pragma unroll
      for (int i = 0; i < 4; i++) {
        af[i] = *(const f16x8*)&As[kk * 4096 + (wm + i * 16 + l16) * 32 + quad * 8];
        bf[i] = *(const f16x8*)&Bs[kk * 4096 + (wn + i * 16 + l16) * 32 + quad * 8];
      }
#pragma unroll
      for (int i = 0; i < 4; i++)
#pragma unroll
        for (int j = 0; j < 4; j++)
          acc[i][j] = __builtin_amdgcn_mfma_f32_16x16x32_f16(af[i], bf[j], acc[i][j], 0, 0, 0);
    }
  }
  const long mb = (long)blockIdx.x * 128 + wm;
  const long nb = (long)blockIdx.y * 128 + wn;
  f16* Cb = C + (long)blockIdx.z * S_ * S_;
#pragma unroll
  for (int i = 0; i < 4; i++)
#pragma unroll
    for (int j = 0; j < 4; j++) {
      long m = mb + i * 16 + quad * 4;
      long n = nb + j * 16 + l16;
#pragma unroll
      for (int r = 0; r < 4; r++)
        Cb[(m + r) * S_ + n] = (f16)(acc[i][j][r] * 0.03125f);
    }
}

// ---------------------------------------------------------------------------
// Fused softmax + AV GEMM. Block (mtile, ntile, z) computes out[z][mtile*128..]
// [ntile*128..]. Its A-tile (raw quantized scores) spans the FULL K=S_ row, so:
//   pass 1: per-row online max & sum-of-exp over 2048 cols (2 threads/row);
//   K-loop: transform scores -> fp16(exp(s-m)/l) in registers, ds_write into
//           the proven LDS layout; B (vT) staged via global_load_lds as before.
// Eliminates the separate softmax kernel and the 32MB attn write/read.
__global__ __launch_bounds__(256, 2)
void attn_av(const f16* __restrict__ sc, const f16* __restrict__ vT,
             float* __restrict__ out) {
  __shared__ __align__(16) f16 As[2 * 128 * 32];
  __shared__ __align__(16) f16 Bs[2 * 128 * 32];
  __shared__ float pm[128][2], pl[128][2];
  __shared__ float mrow[128], lrow[128];  // lrow holds 1/l
  const int t = threadIdx.x;
  const int z = blockIdx.z;
  const f16* Arow = sc + (long)z * S_ * S_ + (long)blockIdx.x * 128 * S_;
  const f16* Bb = vT + (long)z * H_ * S_ + (long)blockIdx.y * 128 * S_;

  // ---- pass 1: row stats ----
  {
    const int row = t >> 1, hf = t & 1;
    const f16* p = Arow + (long)row * S_ + hf * 1024;
    float m = -3.0e38f, l = 0.f;
    for (int c = 0; c < 128; c++) {
      f16x8 v = ((const f16x8*)p)[c];
#pragma unroll
      for (int e = 0; e < 8; e++) {
        float f = (float)v[e];
        if (f > m) { l *= __expf(m - f); m = f; }  // rare after warmup
        l += __expf(f - m);
      }
    }
    pm[row][hf] = m; pl[row][hf] = l;
  }
  __syncthreads();
  if (t < 128) {
    float ma = pm[t][0], mb2 = pm[t][1];
    float m = fmaxf(ma, mb2);
    float l = pl[t][0] * __expf(ma - m) + pl[t][1] * __expf(mb2 - m);
    mrow[t] = m; lrow[t] = 1.0f / l;
  }

  // ---- pass 2: K-loop with on-the-fly attn quantize ----
  const int wave = t >> 6, lane = t & 63;
  const int quad = lane >> 4, l16 = lane & 15;
  const int wm = (wave & 1) * 64, wn = (wave >> 1) * 64;
  const int r0 = t >> 2, c8 = (t & 3) * 8;
  f32x4 acc[4][4] = {};
  for (int k0 = 0; k0 < S_; k0 += 64) {
    __syncthreads();  // also makes mrow/lrow visible on first iter
    {
      const f16* pr0 = Arow + (long)r0 * S_ + k0 + c8;
      const f16* pr1 = Arow + (long)(r0 + 64) * S_ + k0 + c8;
      float m0 = mrow[r0], i0 = lrow[r0];
      float m1 = mrow[r0 + 64], i1 = lrow[r0 + 64];
      f16x8 v00 = *(const f16x8*)pr0;
      f16x8 v01 = *(const f16x8*)(pr0 + 32);
      f16x8 v10 = *(const f16x8*)pr1;
      f16x8 v11 = *(const f16x8*)(pr1 + 32);
      f16x8 o00, o01, o10, o11;
#pragma unroll
      for (int e = 0; e < 8; e++) {
        o00[e] = (f16)(__expf((float)v00[e] - m0) * i0);
        o01[e] = (f16)(__expf((float)v01[e] - m0) * i0);
        o10[e] = (f16)(__expf((float)v10[e] - m1) * i1);
        o11[e] = (f16)(__expf((float)v11[e] - m1) * i1);
      }
      *(f16x8*)&As[t * 8]        = o00;  // [r0][k0+c8]
      *(f16x8*)&As[2048 + t * 8] = o10;  // [r0+64][k0+c8]
      *(f16x8*)&As[4096 + t * 8] = o01;  // [r0][k0+32+c8]
      *(f16x8*)&As[6144 + t * 8] = o11;  // [r0+64][k0+32+c8]
    }
    stage16(Bb + (long)r0 * S_ + k0 + c8,             Bs + t * 8);
    stage16(Bb + (long)(r0 + 64) * S_ + k0 + c8,      Bs + 2048 + t * 8);
    stage16(Bb + (long)r0 * S_ + k0 + 32 + c8,        Bs + 4096 + t * 8);
    stage16(Bb + (long)(r0 + 64) * S_ + k0 + 32 + c8, Bs + 6144 + t * 8);
    __syncthreads();
#pragma unroll
    for (int kk = 0; kk < 2; kk++) {
      f16x8 af[4], bf[4];
#pragma unroll
      for (int i = 0; i < 4; i++) {
        af[i] = *(const f16x8*)&As[kk * 4096 + (wm + i * 16 + l16) * 32 + quad * 8];
        bf[i] = *(const f16x8*)&Bs[kk * 4096 + (wn + i * 16 + l16) * 32 + quad * 8];
      }
#pragma unroll
      for (int i = 0; i < 4; i++)
#pragma unroll
        for (int j = 0; j < 4; j++)
          acc[i][j] = __builtin_amdgcn_mfma_f32_16x16x32_f16(af[i], bf[j], acc[i][j], 0, 0, 0);
    }
  }
  const long mb = (long)blockIdx.x * 128 + wm;
  const long nb = (long)blockIdx.y * 128 + wn;
  float* Ob = out + (long)z * S_ * H_;
#pragma unroll
  for (int i = 0; i < 4; i++)
#pragma unroll
    for (int j = 0; j < 4; j++) {
      long m = mb + i * 16 + quad * 4;
      long n = nb + j * 16 + l16;
#pragma unroll
      for (int r = 0; r < 4; r++)
        Ob[(m + r) * H_ + n] = acc[i][j][r];
    }
}

// ---------------------------------------------------------------------------
extern "C" void kernel_launch(void* const* d_in, const int* in_sizes, int n_in,
                              void* d_out, int out_size, void* d_ws, size_t ws_size,
                              hipStream_t stream) {
  (void)in_sizes; (void)n_in; (void)out_size; (void)ws_size;
  const float* x  = (const float*)d_in[0];
  const float* Wq = (const float*)d_in[1];
  const float* bq = (const float*)d_in[2];
  const float* Wk = (const float*)d_in[3];
  const float* bk = (const float*)d_in[4];
  const float* Wv = (const float*)d_in[5];
  const float* bv = (const float*)d_in[6];

  char* ws = (char*)d_ws;
  f16* xh  = (f16*)ws; ws += (size_t)M_ * H_ * 2;          // 16 MiB
  f16* Wh  = (f16*)ws; ws += (size_t)3 * H_ * H_ * 2;      // 6 MiB
  f16* qkv = (f16*)ws; ws += (size_t)2 * M_ * H_ * 2;      // 32 MiB (q, k)
  f16* vT  = (f16*)ws; ws += (size_t)B_ * H_ * S_ * 2;     // 16 MiB
  f16* sc  = (f16*)ws; ws += (size_t)B_ * S_ * S_ * 2;     // 32 MiB (raw scores)

  // 1) x, Wq/Wk/Wv -> fp16 in one launch
  downconvert_all<<<M_ * H_ / 1024 + 3 * H_ * H_ / 1024, 256, 0, stream>>>(
      x, Wq, Wk, Wv, xh, Wh);

  // 2) fused QKV projection + bias + quantize; V written transposed
  qkv_gemm<<<dim3(64, 24), 256, 0, stream>>>(xh, Wh, bq, bk, bv, qkv, vT);

  // 3) scores = quantize(q @ k^T / 32), per batch
  gemm_qk<<<dim3(16, 16, 4), 256, 0, stream>>>(qkv, qkv + (size_t)M_ * H_, sc);

  // 4) out = quantize(softmax(sc)) @ vT^T  (softmax fused into AV)
  attn_av<<<dim3(16, 8, 4), 256, 0, stream>>>(sc, vT, (float*)d_out);
}